// Round 10
// baseline (59.352 us; speedup 1.0000x reference)
//
#include <hip/hip_runtime.h>
#include <hip/hip_bf16.h>

// ---------------- problem constants ----------------
#define S_LEN 4096
#define IN_DIM 768
#define D_DIM 512
#define N_HEADS 8
#define H_DIM 64
#define TSE_DIM 1536   // 3*DIM

typedef __attribute__((ext_vector_type(8))) short frag8;   // 8 bf16 = 4 VGPRs
typedef __attribute__((ext_vector_type(4))) float f32x4;

__device__ __forceinline__ unsigned short f2bfbits(float f) {
    unsigned int u = __float_as_uint(f);
    unsigned int r = (u + 0x7FFFu + ((u >> 16) & 1u)) >> 16;
    return (unsigned short)r;
}
__device__ __forceinline__ float bf2f(unsigned short b) {
    return __uint_as_float(((unsigned int)b) << 16);
}

// async global->LDS, 16B per lane. LDS dest wave-uniform; HW adds lane*16.
__device__ __forceinline__ void gload_lds16(const void* g, void* l) {
    __builtin_amdgcn_global_load_lds(
        (const __attribute__((address_space(1))) unsigned int*)g,
        (__attribute__((address_space(3))) unsigned int*)l,
        16, 0, 0);
}

// ---------------- prep: x->bf16 + 3 weight transpose-converts (R5, proven) ----------------
__global__ __launch_bounds__(256) void prep_kernel(
        const float4* __restrict__ x4, ushort4* __restrict__ xb4,
        const float* __restrict__ W_in,  unsigned short* __restrict__ WinT,
        const float* __restrict__ W_tse, unsigned short* __restrict__ WtseT,
        const float* __restrict__ W_out, unsigned short* __restrict__ WoutT) {
    __shared__ float tile[32][33];
    int b = blockIdx.x;
    if (b < 3072) {
        int i = b * 256 + threadIdx.x;
        float4 v = x4[i];
        ushort4 o;
        o.x = f2bfbits(v.x); o.y = f2bfbits(v.y);
        o.z = f2bfbits(v.z); o.w = f2bfbits(v.w);
        xb4[i] = o;
        return;
    }
    const float* in; unsigned short* out; int K, N, t;
    if (b < 3456)      { t = b - 3072; in = W_in;  out = WinT;  K = IN_DIM; N = D_DIM;  }
    else if (b < 4224) { t = b - 3456; in = W_tse; out = WtseT; K = D_DIM;  N = TSE_DIM;}
    else               { t = b - 4224; in = W_out; out = WoutT; K = D_DIM;  N = D_DIM;  }
    int ktiles = K / 32;
    int kb = (t % ktiles) * 32, nb = (t / ktiles) * 32;
    int tx = threadIdx.x & 31, ty = threadIdx.x >> 5;
    #pragma unroll
    for (int r = ty; r < 32; r += 8)
        tile[r][tx] = in[(size_t)(kb + r) * N + nb + tx];
    __syncthreads();
    #pragma unroll
    for (int r = ty; r < 32; r += 8)
        out[(size_t)(nb + r) * K + kb + tx] = f2bfbits(tile[tx][r]);
}

// ---------------- bf16 NT-GEMM, ONE WAVE per block, 32x64 tile, barrier-free --------
// C[M][N] = A[M][K]*Bt[N][K]^T (+bias). BK=32. Single wave owns the whole tile:
// no __syncthreads, no vmcnt(0) drain. 3 LDS buffers, stage 2 tiles ahead,
// counted s_waitcnt vmcnt(12) (6 loads/tile x 2 in flight) -- T4 without the barrier.
// LDS layout/frag reads identical geometry to the proven 4-wave kernel.
template<int K, bool OUT_BF16, bool BIAS>
__global__ __launch_bounds__(64) void gemm1w(
        const unsigned short* __restrict__ A,
        const unsigned short* __restrict__ Bt,
        const float* __restrict__ bias,
        void* __restrict__ C,
        int M, int N) {
    constexpr int NT = K >> 5;
    __shared__ __align__(16) unsigned short As[3][32 * 32];   // 3 x 2 KB
    __shared__ __align__(16) unsigned short Bs[3][64 * 32];   // 3 x 4 KB

    const int bm = blockIdx.x * 32;
    const int bn = blockIdx.y * 64;
    const int lane = threadIdx.x;        // 0..63
    const int fr = lane & 15;
    const int fg = lane >> 4;            // k-group 0..3
    const int srow = lane >> 2;          // staging: 16 rows x 32 cols per issue
    const int scol = (lane & 3) * 8;

    const unsigned short* ag = A  + (size_t)(bm + srow) * K + scol;
    const unsigned short* bg = Bt + (size_t)(bn + srow) * K + scol;

    f32x4 acc[2][4];
    #pragma unroll
    for (int mi = 0; mi < 2; ++mi)
        #pragma unroll
        for (int ni = 0; ni < 4; ++ni)
            acc[mi][ni] = (f32x4)(0.f);

    // stage tile t into buffer b: 2 A-issues + 4 B-issues = 6 loads, in tile order
    #define STAGE(t, bf)                                                        \
        {                                                                       \
            _Pragma("unroll")                                                   \
            for (int i = 0; i < 2; ++i)                                         \
                gload_lds16(ag + (size_t)i * 16 * K + (t) * 32, &As[bf][i * 512]); \
            _Pragma("unroll")                                                   \
            for (int i = 0; i < 4; ++i)                                         \
                gload_lds16(bg + (size_t)i * 16 * K + (t) * 32, &Bs[bf][i * 512]); \
        }

    STAGE(0, 0)
    STAGE(1, 1)

    #pragma unroll
    for (int kt = 0; kt < NT; ++kt) {
        if (kt + 2 < NT) STAGE(kt + 2, (kt + 2) % 3)

        // wait until tile kt's 6 loads have landed; keep later tiles in flight
        if (kt + 2 < NT)      asm volatile("s_waitcnt vmcnt(12)" ::: "memory");
        else if (kt + 1 < NT) asm volatile("s_waitcnt vmcnt(6)"  ::: "memory");
        else                  asm volatile("s_waitcnt vmcnt(0)"  ::: "memory");

        const int cb = kt % 3;
        frag8 a[2], b[4];
        #pragma unroll
        for (int mi = 0; mi < 2; ++mi)
            a[mi] = *(const frag8*)&As[cb][(mi * 16 + fr) * 32 + fg * 8];
        #pragma unroll
        for (int ni = 0; ni < 4; ++ni)
            b[ni] = *(const frag8*)&Bs[cb][(ni * 16 + fr) * 32 + fg * 8];
        #pragma unroll
        for (int mi = 0; mi < 2; ++mi)
            #pragma unroll
            for (int ni = 0; ni < 4; ++ni)
                acc[mi][ni] = __builtin_amdgcn_mfma_f32_16x16x32_bf16(
                        a[mi], b[ni], acc[mi][ni], 0, 0, 0);
    }
    #undef STAGE

    // C/D layout col=lane&15, row=(lane>>4)*4+reg  [HW-verified m89/m91]
    #pragma unroll
    for (int mi = 0; mi < 2; ++mi) {
        int grow = bm + mi * 16 + fg * 4;
        #pragma unroll
        for (int ni = 0; ni < 4; ++ni) {
            int gcol = bn + ni * 16 + fr;
            float bv = BIAS ? bias[gcol] : 0.f;
            #pragma unroll
            for (int r = 0; r < 4; ++r) {
                float v = acc[mi][ni][r] + bv;
                if (OUT_BF16)
                    ((unsigned short*)C)[(size_t)(grow + r) * N + gcol] = f2bfbits(v);
                else
                    ((float*)C)[(size_t)(grow + r) * N + gcol] = v;
            }
        }
    }
}

// ---------------- dilated attention: wave <-> s, lane = h*8 + d-chunk (R5, proven) ----
__global__ __launch_bounds__(256) void attn_kernel(
        const unsigned short* __restrict__ tse, unsigned short* __restrict__ out) {
    const int s    = blockIdx.x * 4 + (threadIdx.x >> 6);
    const int lane = threadIdx.x & 63;
    const int off  = (lane >> 3) * H_DIM + (lane & 7) * 8;   // h*64 + d8*8

    float qf[8];
    {
        frag8 q = *(const frag8*)(tse + (size_t)s * TSE_DIM + off);
        #pragma unroll
        for (int i = 0; i < 8; ++i) qf[i] = bf2f((unsigned short)q[i]);
    }

    float sc[7];
    #pragma unroll
    for (int j = 0; j < 7; ++j) {
        int t = s + (j - 3) * 8;
        bool valid = (t >= 0) && (t < S_LEN);
        float p = 0.f;
        if (valid) {
            frag8 k = *(const frag8*)(tse + (size_t)t * TSE_DIM + D_DIM + off);
            #pragma unroll
            for (int i = 0; i < 8; ++i) p += qf[i] * bf2f((unsigned short)k[i]);
        }
        p += __shfl_xor(p, 1, 64);
        p += __shfl_xor(p, 2, 64);
        p += __shfl_xor(p, 4, 64);
        sc[j] = valid ? p * 0.125f : -__builtin_inff();
    }

    float m = sc[0];
    #pragma unroll
    for (int j = 1; j < 7; ++j) m = fmaxf(m, sc[j]);

    float w[7], denom = 0.f;
    #pragma unroll
    for (int j = 0; j < 7; ++j) {
        w[j] = (sc[j] == -__builtin_inff()) ? 0.f : __expf(sc[j] - m);
        denom += w[j];
    }
    const float inv = 1.f / denom;

    float of[8];
    #pragma unroll
    for (int i = 0; i < 8; ++i) of[i] = 0.f;
    #pragma unroll
    for (int j = 0; j < 7; ++j) {
        int t = s + (j - 3) * 8;
        if (t >= 0 && t < S_LEN) {
            frag8 v = *(const frag8*)(tse + (size_t)t * TSE_DIM + 2 * D_DIM + off);
            #pragma unroll
            for (int i = 0; i < 8; ++i) of[i] += w[j] * bf2f((unsigned short)v[i]);
        }
    }

    frag8 o;
    #pragma unroll
    for (int i = 0; i < 8; ++i) o[i] = (short)f2bfbits(of[i] * inv);
    *(frag8*)(out + (size_t)s * D_DIM + off) = o;
}

// ---------------- launch ----------------
extern "C" void kernel_launch(void* const* d_in, const int* in_sizes, int n_in,
                              void* d_out, int out_size, void* d_ws, size_t ws_size,
                              hipStream_t stream) {
    (void)in_sizes; (void)n_in; (void)out_size;
    const float* x     = (const float*)d_in[0];
    const float* W_in  = (const float*)d_in[1];
    const float* b_in  = (const float*)d_in[2];
    const float* W_tse = (const float*)d_in[3];
    const float* W_out = (const float*)d_in[4];
    const float* b_out = (const float*)d_in[5];

    char* p = (char*)d_ws;
    unsigned short* xb    = (unsigned short*)p; p += (size_t)S_LEN * IN_DIM * 2;
    unsigned short* WinT  = (unsigned short*)p; p += (size_t)D_DIM * IN_DIM * 2;
    unsigned short* WtseT = (unsigned short*)p; p += (size_t)TSE_DIM * D_DIM * 2;
    unsigned short* WoutT = (unsigned short*)p; p += (size_t)D_DIM * D_DIM * 2;
    unsigned short* h     = (unsigned short*)p; p += (size_t)S_LEN * D_DIM * 2;
    unsigned short* tse   = (unsigned short*)p; p += (size_t)S_LEN * TSE_DIM * 2;
    unsigned short* attn  = (unsigned short*)p; p += (size_t)S_LEN * D_DIM * 2;
    if ((size_t)(p - (char*)d_ws) > ws_size) return;

    // conversions: 3072 + 384 + 768 + 256 = 4480 blocks
    prep_kernel<<<4480, 256, 0, stream>>>(
            (const float4*)x, (ushort4*)xb, W_in, WinT, W_tse, WtseT, W_out, WoutT);

    // h = x @ W_in + b_in   (bf16 out)  -- 1-wave 32x64 tiles, grid (128,8)=1024
    gemm1w<IN_DIM, true, true><<<dim3(S_LEN / 32, D_DIM / 64), 64, 0, stream>>>(
            xb, WinT, b_in, h, S_LEN, D_DIM);
    // tse = h @ W_tse       (bf16 out)  -- grid (128,24)=3072
    gemm1w<D_DIM, true, false><<<dim3(S_LEN / 32, TSE_DIM / 64), 64, 0, stream>>>(
            h, WtseT, nullptr, tse, S_LEN, TSE_DIM);
    // dilated attention     (bf16 out), wave per s
    attn_kernel<<<S_LEN / 4, 256, 0, stream>>>(tse, attn);
    // out = attn @ W_out + b_out  (fp32 out -> d_out)  -- grid (128,8)=1024
    gemm1w<D_DIM, false, true><<<dim3(S_LEN / 32, D_DIM / 64), 64, 0, stream>>>(
            attn, WoutT, b_out, (float*)d_out, S_LEN, D_DIM);
}

// Round 11
// 56.653 us; speedup vs baseline: 1.0476x; 1.0476x over previous
//
#include <hip/hip_runtime.h>
#include <hip/hip_bf16.h>

// ---------------- problem constants ----------------
#define S_LEN 4096
#define IN_DIM 768
#define D_DIM 512
#define N_HEADS 8
#define H_DIM 64
#define TSE_DIM 1536   // 3*DIM

typedef __attribute__((ext_vector_type(8))) short frag8;   // 8 bf16 = 4 VGPRs
typedef __attribute__((ext_vector_type(4))) float f32x4;

__device__ __forceinline__ unsigned short f2bfbits(float f) {
    unsigned int u = __float_as_uint(f);
    unsigned int r = (u + 0x7FFFu + ((u >> 16) & 1u)) >> 16;
    return (unsigned short)r;
}
__device__ __forceinline__ float bf2f(unsigned short b) {
    return __uint_as_float(((unsigned int)b) << 16);
}

// async global->LDS, 16B per lane. LDS dest wave-uniform; HW adds lane*16.
__device__ __forceinline__ void gload_lds16(const void* g, void* l) {
    __builtin_amdgcn_global_load_lds(
        (const __attribute__((address_space(1))) unsigned int*)g,
        (__attribute__((address_space(3))) unsigned int*)l,
        16, 0, 0);
}

// ---------------- prep: x->bf16 + 3 weight transpose-converts (R5, proven) ----------------
__global__ __launch_bounds__(256) void prep_kernel(
        const float4* __restrict__ x4, ushort4* __restrict__ xb4,
        const float* __restrict__ W_in,  unsigned short* __restrict__ WinT,
        const float* __restrict__ W_tse, unsigned short* __restrict__ WtseT,
        const float* __restrict__ W_out, unsigned short* __restrict__ WoutT) {
    __shared__ float tile[32][33];
    int b = blockIdx.x;
    if (b < 3072) {
        int i = b * 256 + threadIdx.x;
        float4 v = x4[i];
        ushort4 o;
        o.x = f2bfbits(v.x); o.y = f2bfbits(v.y);
        o.z = f2bfbits(v.z); o.w = f2bfbits(v.w);
        xb4[i] = o;
        return;
    }
    const float* in; unsigned short* out; int K, N, t;
    if (b < 3456)      { t = b - 3072; in = W_in;  out = WinT;  K = IN_DIM; N = D_DIM;  }
    else if (b < 4224) { t = b - 3456; in = W_tse; out = WtseT; K = D_DIM;  N = TSE_DIM;}
    else               { t = b - 4224; in = W_out; out = WoutT; K = D_DIM;  N = D_DIM;  }
    int ktiles = K / 32;
    int kb = (t % ktiles) * 32, nb = (t / ktiles) * 32;
    int tx = threadIdx.x & 31, ty = threadIdx.x >> 5;
    #pragma unroll
    for (int r = ty; r < 32; r += 8)
        tile[r][tx] = in[(size_t)(kb + r) * N + nb + tx];
    __syncthreads();
    #pragma unroll
    for (int r = ty; r < 32; r += 8)
        out[(size_t)(nb + r) * K + kb + tx] = f2bfbits(tile[tx][r]);
}

// ---------------- bf16 NT-GEMM, 64x64 tile, TWO K-tiles per barrier ----------------
// C[M][N] = A[M][K]*Bt[N][K]^T (+bias). BK=32, 4 waves (2x2), wave = 32x32 = 2x2 frags.
// 4 LDS buffer-pairs (2 sets x 2 tiles): iter p stages pair p+1 into set (p+1)&1,
// computes pair p from set p&1, ONE __syncthreads per pair -> barrier-drain stalls halve
// vs R5 while keeping R5's proven shape/occupancy. FP order identical to R5.
template<int K, bool OUT_BF16, bool BIAS>
__global__ __launch_bounds__(256) void gemm_nt(
        const unsigned short* __restrict__ A,
        const unsigned short* __restrict__ Bt,
        const float* __restrict__ bias,
        void* __restrict__ C,
        int M, int N) {
    constexpr int NT = K >> 5;           // 32-wide K-tiles
    constexpr int NP = NT >> 1;          // pairs (K=768->12, K=512->8)
    __shared__ __align__(16) unsigned short As[4][64 * 32];   // 16 KB
    __shared__ __align__(16) unsigned short Bs[4][64 * 32];   // 16 KB

    const int bm = blockIdx.x * 64;
    const int bn = blockIdx.y * 64;
    const int lane = threadIdx.x & 63;
    const int wave = threadIdx.x >> 6;
    const int wr = wave >> 1;            // 0..1 (32 rows each)
    const int wc = wave & 1;             // 0..1 (32 cols each)
    const int fr = lane & 15;
    const int fg = lane >> 4;            // k-group 0..3

    const int srow = lane >> 2;          // staging: chunk = 16 rows x 32 cols = 1024B
    const int scol = (lane & 3) * 8;

    // wave w stages rows [16w, 16w+16) of each A/B tile
    const unsigned short* agp = A  + (size_t)(bm + wave * 16 + srow) * K + scol;
    const unsigned short* bgp = Bt + (size_t)(bn + wave * 16 + srow) * K + scol;

    f32x4 acc[2][2];
    #pragma unroll
    for (int mi = 0; mi < 2; ++mi)
        #pragma unroll
        for (int ni = 0; ni < 2; ++ni)
            acc[mi][ni] = (f32x4)(0.f);

    // stage K-tile t into buffer b (one A-issue + one B-issue per wave)
    #define STAGE(t, b)                                          \
        gload_lds16(agp + (t) * 32, &As[b][wave * 512]);         \
        gload_lds16(bgp + (t) * 32, &Bs[b][wave * 512]);

    // compute K-tile from buffer b into acc
    #define COMPUTE(b)                                                           \
        {                                                                        \
            frag8 a_[2], b_[2];                                                  \
            _Pragma("unroll")                                                    \
            for (int mi = 0; mi < 2; ++mi)                                       \
                a_[mi] = *(const frag8*)&As[b][(wr * 32 + mi * 16 + fr) * 32 + fg * 8]; \
            _Pragma("unroll")                                                    \
            for (int ni = 0; ni < 2; ++ni)                                       \
                b_[ni] = *(const frag8*)&Bs[b][(wc * 32 + ni * 16 + fr) * 32 + fg * 8]; \
            _Pragma("unroll")                                                    \
            for (int mi = 0; mi < 2; ++mi)                                       \
                _Pragma("unroll")                                                \
                for (int ni = 0; ni < 2; ++ni)                                   \
                    acc[mi][ni] = __builtin_amdgcn_mfma_f32_16x16x32_bf16(       \
                            a_[mi], b_[ni], acc[mi][ni], 0, 0, 0);               \
        }

    // prologue: stage pair 0 (tiles 0,1) into set 0
    STAGE(0, 0)
    STAGE(1, 1)
    __syncthreads();

    #pragma unroll
    for (int p = 0; p < NP; ++p) {
        const int s0 = (p & 1) * 2;          // set holding pair p
        if (p + 1 < NP) {
            const int s1 = ((p + 1) & 1) * 2;
            STAGE(2 * p + 2, s1 + 0)
            STAGE(2 * p + 3, s1 + 1)
        }
        COMPUTE(s0 + 0)
        COMPUTE(s0 + 1)
        if (p + 1 < NP) __syncthreads();     // drains prefetch; set s1 ready
    }
    #undef STAGE
    #undef COMPUTE

    // C/D layout col=lane&15, row=(lane>>4)*4+reg  [HW-verified m89/m91]
    #pragma unroll
    for (int mi = 0; mi < 2; ++mi) {
        int grow = bm + wr * 32 + mi * 16 + fg * 4;
        #pragma unroll
        for (int ni = 0; ni < 2; ++ni) {
            int gcol = bn + wc * 32 + ni * 16 + fr;
            float bv = BIAS ? bias[gcol] : 0.f;
            #pragma unroll
            for (int r = 0; r < 4; ++r) {
                float v = acc[mi][ni][r] + bv;
                if (OUT_BF16)
                    ((unsigned short*)C)[(size_t)(grow + r) * N + gcol] = f2bfbits(v);
                else
                    ((float*)C)[(size_t)(grow + r) * N + gcol] = v;
            }
        }
    }
}

// ---------------- dilated attention: wave <-> s, lane = h*8 + d-chunk (R5, proven) ----
__global__ __launch_bounds__(256) void attn_kernel(
        const unsigned short* __restrict__ tse, unsigned short* __restrict__ out) {
    const int s    = blockIdx.x * 4 + (threadIdx.x >> 6);
    const int lane = threadIdx.x & 63;
    const int off  = (lane >> 3) * H_DIM + (lane & 7) * 8;   // h*64 + d8*8

    float qf[8];
    {
        frag8 q = *(const frag8*)(tse + (size_t)s * TSE_DIM + off);
        #pragma unroll
        for (int i = 0; i < 8; ++i) qf[i] = bf2f((unsigned short)q[i]);
    }

    float sc[7];
    #pragma unroll
    for (int j = 0; j < 7; ++j) {
        int t = s + (j - 3) * 8;
        bool valid = (t >= 0) && (t < S_LEN);
        float p = 0.f;
        if (valid) {
            frag8 k = *(const frag8*)(tse + (size_t)t * TSE_DIM + D_DIM + off);
            #pragma unroll
            for (int i = 0; i < 8; ++i) p += qf[i] * bf2f((unsigned short)k[i]);
        }
        p += __shfl_xor(p, 1, 64);
        p += __shfl_xor(p, 2, 64);
        p += __shfl_xor(p, 4, 64);
        sc[j] = valid ? p * 0.125f : -__builtin_inff();
    }

    float m = sc[0];
    #pragma unroll
    for (int j = 1; j < 7; ++j) m = fmaxf(m, sc[j]);

    float w[7], denom = 0.f;
    #pragma unroll
    for (int j = 0; j < 7; ++j) {
        w[j] = (sc[j] == -__builtin_inff()) ? 0.f : __expf(sc[j] - m);
        denom += w[j];
    }
    const float inv = 1.f / denom;

    float of[8];
    #pragma unroll
    for (int i = 0; i < 8; ++i) of[i] = 0.f;
    #pragma unroll
    for (int j = 0; j < 7; ++j) {
        int t = s + (j - 3) * 8;
        if (t >= 0 && t < S_LEN) {
            frag8 v = *(const frag8*)(tse + (size_t)t * TSE_DIM + 2 * D_DIM + off);
            #pragma unroll
            for (int i = 0; i < 8; ++i) of[i] += w[j] * bf2f((unsigned short)v[i]);
        }
    }

    frag8 o;
    #pragma unroll
    for (int i = 0; i < 8; ++i) o[i] = (short)f2bfbits(of[i] * inv);
    *(frag8*)(out + (size_t)s * D_DIM + off) = o;
}

// ---------------- launch ----------------
extern "C" void kernel_launch(void* const* d_in, const int* in_sizes, int n_in,
                              void* d_out, int out_size, void* d_ws, size_t ws_size,
                              hipStream_t stream) {
    (void)in_sizes; (void)n_in; (void)out_size;
    const float* x     = (const float*)d_in[0];
    const float* W_in  = (const float*)d_in[1];
    const float* b_in  = (const float*)d_in[2];
    const float* W_tse = (const float*)d_in[3];
    const float* W_out = (const float*)d_in[4];
    const float* b_out = (const float*)d_in[5];

    char* p = (char*)d_ws;
    unsigned short* xb    = (unsigned short*)p; p += (size_t)S_LEN * IN_DIM * 2;
    unsigned short* WinT  = (unsigned short*)p; p += (size_t)D_DIM * IN_DIM * 2;
    unsigned short* WtseT = (unsigned short*)p; p += (size_t)TSE_DIM * D_DIM * 2;
    unsigned short* WoutT = (unsigned short*)p; p += (size_t)D_DIM * D_DIM * 2;
    unsigned short* h     = (unsigned short*)p; p += (size_t)S_LEN * D_DIM * 2;
    unsigned short* tse   = (unsigned short*)p; p += (size_t)S_LEN * TSE_DIM * 2;
    unsigned short* attn  = (unsigned short*)p; p += (size_t)S_LEN * D_DIM * 2;
    if ((size_t)(p - (char*)d_ws) > ws_size) return;

    // conversions: 3072 + 384 + 768 + 256 = 4480 blocks
    prep_kernel<<<4480, 256, 0, stream>>>(
            (const float4*)x, (ushort4*)xb, W_in, WinT, W_tse, WtseT, W_out, WoutT);

    // h = x @ W_in + b_in   (bf16 out)  -- grid (64,8)=512 blocks
    gemm_nt<IN_DIM, true, true><<<dim3(S_LEN / 64, D_DIM / 64), 256, 0, stream>>>(
            xb, WinT, b_in, h, S_LEN, D_DIM);
    // tse = h @ W_tse       (bf16 out)  -- grid (64,24)=1536 blocks
    gemm_nt<D_DIM, true, false><<<dim3(S_LEN / 64, TSE_DIM / 64), 256, 0, stream>>>(
            h, WtseT, nullptr, tse, S_LEN, TSE_DIM);
    // dilated attention     (bf16 out), wave per s
    attn_kernel<<<S_LEN / 4, 256, 0, stream>>>(tse, attn);
    // out = attn @ W_out + b_out  (fp32 out -> d_out)  -- grid (64,8)
    gemm_nt<D_DIM, false, true><<<dim3(S_LEN / 64, D_DIM / 64), 256, 0, stream>>>(
            attn, WoutT, b_out, (float*)d_out, S_LEN, D_DIM);
}

// Round 12
// 56.254 us; speedup vs baseline: 1.0551x; 1.0071x over previous
//
#include <hip/hip_runtime.h>
#include <hip/hip_bf16.h>

// ---------------- problem constants ----------------
#define S_LEN 4096
#define IN_DIM 768
#define D_DIM 512
#define N_HEADS 8
#define H_DIM 64
#define TSE_DIM 1536   // 3*DIM

typedef __attribute__((ext_vector_type(8))) short frag8;   // 8 bf16 = 4 VGPRs
typedef __attribute__((ext_vector_type(4))) float f32x4;

__device__ __forceinline__ unsigned short f2bfbits(float f) {
    unsigned int u = __float_as_uint(f);
    unsigned int r = (u + 0x7FFFu + ((u >> 16) & 1u)) >> 16;
    return (unsigned short)r;
}
__device__ __forceinline__ float bf2f(unsigned short b) {
    return __uint_as_float(((unsigned int)b) << 16);
}

// async global->LDS, 16B per lane. LDS dest wave-uniform; HW adds lane*16.
__device__ __forceinline__ void gload_lds16(const void* g, void* l) {
    __builtin_amdgcn_global_load_lds(
        (const __attribute__((address_space(1))) unsigned int*)g,
        (__attribute__((address_space(3))) unsigned int*)l,
        16, 0, 0);
}

// ---------------- prep: x->bf16 + 3 weights -> FRAG-MAJOR bf16 ----------------
// Frag-major: for n-group G (16 cols of W) and k-step kt (32 rows of W), a 1024B
// chunk at Bp[(G*NT + kt)*512 + l*8] holds lane l's MFMA B-fragment:
//   chunk[l*8 + j] = W[kt*32 + (l>>4)*8 + j][G*16 + (l&15)]
// so a wave's b-frag load is ONE coalesced global_load_dwordx4 (no LDS round-trip).
// block ranges: [0,3072) x-cvt | [3072,3456) W_in | [3456,4224) W_tse | [4224,4480) W_out
__global__ __launch_bounds__(256) void prep_kernel(
        const float4* __restrict__ x4, ushort4* __restrict__ xb4,
        const float* __restrict__ W_in,  unsigned short* __restrict__ WinP,
        const float* __restrict__ W_tse, unsigned short* __restrict__ WtseP,
        const float* __restrict__ W_out, unsigned short* __restrict__ WoutP) {
    __shared__ float tile[32][33];
    int b = blockIdx.x;
    if (b < 3072) {
        int i = b * 256 + threadIdx.x;
        float4 v = x4[i];
        ushort4 o;
        o.x = f2bfbits(v.x); o.y = f2bfbits(v.y);
        o.z = f2bfbits(v.z); o.w = f2bfbits(v.w);
        xb4[i] = o;
        return;
    }
    const float* in; unsigned short* out; int K, N, t;
    if (b < 3456)      { t = b - 3072; in = W_in;  out = WinP;  K = IN_DIM; N = D_DIM;  }
    else if (b < 4224) { t = b - 3456; in = W_tse; out = WtseP; K = D_DIM;  N = TSE_DIM;}
    else               { t = b - 4224; in = W_out; out = WoutP; K = D_DIM;  N = D_DIM;  }
    const int ktiles = K / 32;                 // = NT of the consuming GEMM
    const int kb = (t % ktiles) * 32, nb = (t / ktiles) * 32;
    const int tx = threadIdx.x & 31, ty = threadIdx.x >> 5;
    #pragma unroll
    for (int r = ty; r < 32; r += 8)
        tile[r][tx] = in[(size_t)(kb + r) * N + nb + tx];
    __syncthreads();
    if (threadIdx.x < 128) {
        const int g = threadIdx.x >> 6;        // n-group within this 32-col tile
        const int l = threadIdx.x & 63;        // lane
        frag8 o;
        #pragma unroll
        for (int j = 0; j < 8; ++j)
            o[j] = (short)f2bfbits(tile[(l >> 4) * 8 + j][g * 16 + (l & 15)]);
        *(frag8*)(out + ((size_t)(nb / 16 + g) * ktiles + kb / 32) * 512 + (size_t)l * 8) = o;
    }
}

// ---------------- bf16 GEMM, 64x64 tile: A via LDS dbuf, B via frag-major regs -----
// C[M][N] = A[M][K] * W[K][N] (+bias). BK=32, 4 waves (2x2), wave = 32x32 = 2x2 frags.
// Per K-step per wave: 1 gload_lds (A) + 2 coalesced global b-frag loads (prefetched
// one step ahead) + 2 ds_read_b128 + 4 MFMA. LDS-read pipe halved vs R5.
template<int K, bool OUT_BF16, bool BIAS>
__global__ __launch_bounds__(256) void gemm_bp(
        const unsigned short* __restrict__ A,
        const unsigned short* __restrict__ Bp,    // frag-major weights
        const float* __restrict__ bias,
        void* __restrict__ C,
        int M, int N) {
    constexpr int NT = K >> 5;
    __shared__ __align__(16) unsigned short As[2][64 * 32];   // 8 KB total

    const int bm = blockIdx.x * 64;
    const int bn = blockIdx.y * 64;
    const int lane = threadIdx.x & 63;
    const int wave = threadIdx.x >> 6;
    const int wr = wave >> 1;            // 0..1 (32 rows each)
    const int wc = wave & 1;             // 0..1 (32 cols each)
    const int fr = lane & 15;
    const int fg = lane >> 4;            // k-group 0..3
    const int srow = lane >> 2;          // A staging: 16 rows x 32 cols per wave
    const int scol = (lane & 3) * 8;

    const unsigned short* agp = A + (size_t)(bm + wave * 16 + srow) * K + scol;
    const unsigned short* bb0 =
        Bp + ((size_t)((bn >> 4) + wc * 2 + 0) * NT) * 512 + lane * 8;
    const unsigned short* bb1 =
        Bp + ((size_t)((bn >> 4) + wc * 2 + 1) * NT) * 512 + lane * 8;

    f32x4 acc[2][2];
    #pragma unroll
    for (int mi = 0; mi < 2; ++mi)
        #pragma unroll
        for (int ni = 0; ni < 2; ++ni)
            acc[mi][ni] = (f32x4)(0.f);

    // prologue: stage A tile 0, load B frags for step 0
    gload_lds16(agp, &As[0][wave * 512]);
    frag8 bc0 = *(const frag8*)bb0;
    frag8 bc1 = *(const frag8*)bb1;
    __syncthreads();

    int cur = 0;
    #pragma unroll
    for (int kt = 0; kt < NT; ++kt) {
        frag8 bq0, bq1;
        if (kt + 1 < NT) {
            gload_lds16(agp + (kt + 1) * 32, &As[cur ^ 1][wave * 512]);
            bq0 = *(const frag8*)(bb0 + (size_t)(kt + 1) * 512);
            bq1 = *(const frag8*)(bb1 + (size_t)(kt + 1) * 512);
        }

        frag8 a0 = *(const frag8*)&As[cur][(wr * 32 + 0  + fr) * 32 + fg * 8];
        frag8 a1 = *(const frag8*)&As[cur][(wr * 32 + 16 + fr) * 32 + fg * 8];
        acc[0][0] = __builtin_amdgcn_mfma_f32_16x16x32_bf16(a0, bc0, acc[0][0], 0, 0, 0);
        acc[0][1] = __builtin_amdgcn_mfma_f32_16x16x32_bf16(a0, bc1, acc[0][1], 0, 0, 0);
        acc[1][0] = __builtin_amdgcn_mfma_f32_16x16x32_bf16(a1, bc0, acc[1][0], 0, 0, 0);
        acc[1][1] = __builtin_amdgcn_mfma_f32_16x16x32_bf16(a1, bc1, acc[1][1], 0, 0, 0);

        if (kt + 1 < NT) {
            __syncthreads();
            cur ^= 1;
            bc0 = bq0; bc1 = bq1;
        }
    }

    // C/D layout col=lane&15, row=(lane>>4)*4+reg  [HW-verified m89/m91]
    #pragma unroll
    for (int mi = 0; mi < 2; ++mi) {
        int grow = bm + wr * 32 + mi * 16 + fg * 4;
        #pragma unroll
        for (int ni = 0; ni < 2; ++ni) {
            int gcol = bn + wc * 32 + ni * 16 + fr;
            float bv = BIAS ? bias[gcol] : 0.f;
            #pragma unroll
            for (int r = 0; r < 4; ++r) {
                float v = acc[mi][ni][r] + bv;
                if (OUT_BF16)
                    ((unsigned short*)C)[(size_t)(grow + r) * N + gcol] = f2bfbits(v);
                else
                    ((float*)C)[(size_t)(grow + r) * N + gcol] = v;
            }
        }
    }
}

// ---------------- dilated attention: wave <-> s, lane = h*8 + d-chunk (proven) ----
__global__ __launch_bounds__(256) void attn_kernel(
        const unsigned short* __restrict__ tse, unsigned short* __restrict__ out) {
    const int s    = blockIdx.x * 4 + (threadIdx.x >> 6);
    const int lane = threadIdx.x & 63;
    const int off  = (lane >> 3) * H_DIM + (lane & 7) * 8;   // h*64 + d8*8

    float qf[8];
    {
        frag8 q = *(const frag8*)(tse + (size_t)s * TSE_DIM + off);
        #pragma unroll
        for (int i = 0; i < 8; ++i) qf[i] = bf2f((unsigned short)q[i]);
    }

    float sc[7];
    #pragma unroll
    for (int j = 0; j < 7; ++j) {
        int t = s + (j - 3) * 8;
        bool valid = (t >= 0) && (t < S_LEN);
        float p = 0.f;
        if (valid) {
            frag8 k = *(const frag8*)(tse + (size_t)t * TSE_DIM + D_DIM + off);
            #pragma unroll
            for (int i = 0; i < 8; ++i) p += qf[i] * bf2f((unsigned short)k[i]);
        }
        p += __shfl_xor(p, 1, 64);
        p += __shfl_xor(p, 2, 64);
        p += __shfl_xor(p, 4, 64);
        sc[j] = valid ? p * 0.125f : -__builtin_inff();
    }

    float m = sc[0];
    #pragma unroll
    for (int j = 1; j < 7; ++j) m = fmaxf(m, sc[j]);

    float w[7], denom = 0.f;
    #pragma unroll
    for (int j = 0; j < 7; ++j) {
        w[j] = (sc[j] == -__builtin_inff()) ? 0.f : __expf(sc[j] - m);
        denom += w[j];
    }
    const float inv = 1.f / denom;

    float of[8];
    #pragma unroll
    for (int i = 0; i < 8; ++i) of[i] = 0.f;
    #pragma unroll
    for (int j = 0; j < 7; ++j) {
        int t = s + (j - 3) * 8;
        if (t >= 0 && t < S_LEN) {
            frag8 v = *(const frag8*)(tse + (size_t)t * TSE_DIM + 2 * D_DIM + off);
            #pragma unroll
            for (int i = 0; i < 8; ++i) of[i] += w[j] * bf2f((unsigned short)v[i]);
        }
    }

    frag8 o;
    #pragma unroll
    for (int i = 0; i < 8; ++i) o[i] = (short)f2bfbits(of[i] * inv);
    *(frag8*)(out + (size_t)s * D_DIM + off) = o;
}

// ---------------- launch ----------------
extern "C" void kernel_launch(void* const* d_in, const int* in_sizes, int n_in,
                              void* d_out, int out_size, void* d_ws, size_t ws_size,
                              hipStream_t stream) {
    (void)in_sizes; (void)n_in; (void)out_size;
    const float* x     = (const float*)d_in[0];
    const float* W_in  = (const float*)d_in[1];
    const float* b_in  = (const float*)d_in[2];
    const float* W_tse = (const float*)d_in[3];
    const float* W_out = (const float*)d_in[4];
    const float* b_out = (const float*)d_in[5];

    char* p = (char*)d_ws;
    unsigned short* xb    = (unsigned short*)p; p += (size_t)S_LEN * IN_DIM * 2;
    unsigned short* WinP  = (unsigned short*)p; p += (size_t)IN_DIM * D_DIM * 2;
    unsigned short* WtseP = (unsigned short*)p; p += (size_t)D_DIM * TSE_DIM * 2;
    unsigned short* WoutP = (unsigned short*)p; p += (size_t)D_DIM * D_DIM * 2;
    unsigned short* h     = (unsigned short*)p; p += (size_t)S_LEN * D_DIM * 2;
    unsigned short* tse   = (unsigned short*)p; p += (size_t)S_LEN * TSE_DIM * 2;
    unsigned short* attn  = (unsigned short*)p; p += (size_t)S_LEN * D_DIM * 2;
    if ((size_t)(p - (char*)d_ws) > ws_size) return;

    // conversions: 3072 + 384 + 768 + 256 = 4480 blocks
    prep_kernel<<<4480, 256, 0, stream>>>(
            (const float4*)x, (ushort4*)xb, W_in, WinP, W_tse, WtseP, W_out, WoutP);

    // h = x @ W_in + b_in   (bf16 out)  -- grid (64,8)=512 blocks
    gemm_bp<IN_DIM, true, true><<<dim3(S_LEN / 64, D_DIM / 64), 256, 0, stream>>>(
            xb, WinP, b_in, h, S_LEN, D_DIM);
    // tse = h @ W_tse       (bf16 out)  -- grid (64,24)=1536 blocks
    gemm_bp<D_DIM, true, false><<<dim3(S_LEN / 64, TSE_DIM / 64), 256, 0, stream>>>(
            h, WtseP, nullptr, tse, S_LEN, TSE_DIM);
    // dilated attention     (bf16 out), wave per s
    attn_kernel<<<S_LEN / 4, 256, 0, stream>>>(tse, attn);
    // out = attn @ W_out + b_out  (fp32 out -> d_out)  -- grid (64,8)
    gemm_bp<D_DIM, false, true><<<dim3(S_LEN / 64, D_DIM / 64), 256, 0, stream>>>(
            attn, WoutP, b_out, (float*)d_out, S_LEN, D_DIM);
}